// Round 1
// baseline (128.750 us; speedup 1.0000x reference)
//
#include <hip/hip_runtime.h>
#include <stdint.h>

// Problem shape (fixed by setup_inputs): B=16384, C=2048, D=1024, fp32 in/out.
// out[b,c] = <x_b/||x_b||, a_c/||a_c||>  (eps=1e-8 on the norms)
//
// Strategy: normalize rows in fp32, cast to bf16 into d_ws, then bf16 MFMA GEMM
// (m97 structure: 128x128 tile, BK=64, 4 waves, global_load_lds width=16).

#define D_DIM 1024
#define N_DIM 2048   // C (columns of output)
#define BM 128
#define BN 128
#define BK 64

typedef __bf16 bf16x8 __attribute__((ext_vector_type(8)));
typedef float  f32x4  __attribute__((ext_vector_type(4)));

__device__ __forceinline__ unsigned short f2bf(float f) {
    union { float f; uint32_t u; } v; v.f = f;
    uint32_t r = v.u + 0x7fffu + ((v.u >> 16) & 1u);  // RNE
    return (unsigned short)(r >> 16);
}

// One block per row: 256 threads x float4 = 1024 floats. Reduce, scale, cast to bf16.
__global__ __launch_bounds__(256) void normalize_rows(
        const float* __restrict__ in, unsigned short* __restrict__ out) {
    const int row = blockIdx.x;
    const int t = threadIdx.x;
    const float4 v = ((const float4*)(in + (size_t)row * D_DIM))[t];
    float ss = v.x * v.x + v.y * v.y + v.z * v.z + v.w * v.w;
#pragma unroll
    for (int o = 1; o < 64; o <<= 1) ss += __shfl_xor(ss, o);
    __shared__ float red[4];
    if ((t & 63) == 0) red[t >> 6] = ss;
    __syncthreads();
    const float tot = red[0] + red[1] + red[2] + red[3];
    const float scale = 1.0f / fmaxf(sqrtf(tot), 1e-8f);
    ushort4 o;
    o.x = f2bf(v.x * scale);
    o.y = f2bf(v.y * scale);
    o.z = f2bf(v.z * scale);
    o.w = f2bf(v.w * scale);
    ((ushort4*)(out + (size_t)row * D_DIM))[t] = o;
}

__device__ __forceinline__ void gload_lds16(const void* g, void* l) {
    __builtin_amdgcn_global_load_lds(
        (const __attribute__((address_space(1))) void*)g,
        (__attribute__((address_space(3))) void*)l,
        16, 0, 0);
}

// A: [M][K] bf16 (normalized inputs), Bm: [N][K] bf16 (normalized class_avgs),
// Cg: [M][N] fp32. Grid = (M/BM)*(N/BN), 256 threads (4 waves, 2x2 over tile).
__global__ __launch_bounds__(256) void gemm_bt(
        const unsigned short* __restrict__ A,
        const unsigned short* __restrict__ Bm,
        float* __restrict__ Cg) {
    // XCD-bijective swizzle (nwg % 8 == 0 here: 128*16 = 2048)
    const int nwg = gridDim.x;
    const int cpx = nwg >> 3;
    const int wg  = (blockIdx.x & 7) * cpx + (blockIdx.x >> 3);
    const int bm  = wg >> 4;          // N_DIM/BN == 16 tiles per row
    const int bn  = wg & 15;

    __shared__ unsigned short As[BM * BK];  // [128][64]
    __shared__ unsigned short Bs[BN * BK];  // [128][64]

    const int tid  = threadIdx.x;
    const int lane = tid & 63;
    const int wv   = tid >> 6;
    const int wr   = wv >> 1;   // wave row (0..1) -> 64-row half
    const int wc   = wv & 1;    // wave col (0..1) -> 64-col half

    const int rowA = bm * BM;
    const int rowB = bn * BN;

    const int lrow_in = lane >> 3;        // 0..7: row within 8-row group
    const int lcol_in = (lane & 7) * 8;   // element col (8 bf16 = 16B per lane)

    f32x4 acc[4][4] = {};

    for (int k0 = 0; k0 < D_DIM; k0 += BK) {
#pragma unroll
        for (int i = 0; i < 4; ++i) {
            const int r = i * 32 + wv * 8;  // wave-uniform LDS row base
            gload_lds16(&A [(size_t)(rowA + r + lrow_in) * D_DIM + k0 + lcol_in], &As[r * BK]);
            gload_lds16(&Bm[(size_t)(rowB + r + lrow_in) * D_DIM + k0 + lcol_in], &Bs[r * BK]);
        }
        __syncthreads();  // drains vmcnt(0) before barrier

#pragma unroll
        for (int kk = 0; kk < 2; ++kk) {
            const int kof = kk * 32 + (lane >> 4) * 8;
            bf16x8 af[4], bfr[4];
#pragma unroll
            for (int m = 0; m < 4; ++m)
                af[m] = *(const bf16x8*)&As[(wr * 64 + m * 16 + (lane & 15)) * BK + kof];
#pragma unroll
            for (int n = 0; n < 4; ++n)
                bfr[n] = *(const bf16x8*)&Bs[(wc * 64 + n * 16 + (lane & 15)) * BK + kof];
#pragma unroll
            for (int m = 0; m < 4; ++m)
#pragma unroll
                for (int n = 0; n < 4; ++n)
                    acc[m][n] = __builtin_amdgcn_mfma_f32_16x16x32_bf16(
                        af[m], bfr[n], acc[m][n], 0, 0, 0);
        }
        __syncthreads();
    }

    // C/D layout (m89-verified): col = lane&15, row = (lane>>4)*4 + reg
    const int crow0 = rowA + wr * 64 + (lane >> 4) * 4;
    const int ccol0 = rowB + wc * 64 + (lane & 15);
#pragma unroll
    for (int m = 0; m < 4; ++m)
#pragma unroll
        for (int n = 0; n < 4; ++n)
#pragma unroll
            for (int j = 0; j < 4; ++j)
                Cg[(size_t)(crow0 + m * 16 + j) * N_DIM + ccol0 + n * 16] = acc[m][n][j];
}

extern "C" void kernel_launch(void* const* d_in, const int* in_sizes, int n_in,
                              void* d_out, int out_size, void* d_ws, size_t ws_size,
                              hipStream_t stream) {
    const float* x = (const float*)d_in[0];   // [B, D]
    const float* a = (const float*)d_in[1];   // [C, D]
    float* out = (float*)d_out;               // [B, C]

    const int Bn = in_sizes[0] / D_DIM;  // 16384
    const int Cn = in_sizes[1] / D_DIM;  // 2048

    unsigned short* xn = (unsigned short*)d_ws;            // [B][D] bf16
    unsigned short* an = xn + (size_t)Bn * D_DIM;          // [C][D] bf16

    normalize_rows<<<Bn, 256, 0, stream>>>(x, xn);
    normalize_rows<<<Cn, 256, 0, stream>>>(a, an);

    const int grid = (Bn / BM) * (Cn / BN);  // 128 * 16 = 2048
    gemm_bt<<<grid, 256, 0, stream>>>(xn, an, out);
}

// Round 2
// 103.355 us; speedup vs baseline: 1.2457x; 1.2457x over previous
//
#include <hip/hip_runtime.h>
#include <stdint.h>

// out[b,c] = <x_b/||x_b||, a_c/||a_c||>, B=16384, C=2048, D=1024, fp32 in/out.
// Pass 1: fp32 row-normalize -> bf16 into d_ws.
// Pass 2: bf16 MFMA GEMM, 256x256 tile, BK=32, 8 waves (2Mx4N), quad-buffered
//         LDS (4 x 32KB), counted vmcnt(8) once per K-tile (T3+T4), LDS XOR
//         swizzle (T2), setprio around MFMA clusters (T5), chunked XCD swizzle (T1).

#define D_DIM 1024
#define N_DIM 2048
#define BMt 256
#define BNt 256
#define BKt 32
#define NTILES 32   // D_DIM / BKt

typedef __bf16 bf16x8 __attribute__((ext_vector_type(8)));
typedef float  f32x4  __attribute__((ext_vector_type(4)));

__device__ __forceinline__ unsigned short f2bf(float f) {
    union { float f; uint32_t u; } v; v.f = f;
    uint32_t r = v.u + 0x7fffu + ((v.u >> 16) & 1u);  // RNE
    return (unsigned short)(r >> 16);
}

__global__ __launch_bounds__(256) void normalize_rows(
        const float* __restrict__ in, unsigned short* __restrict__ out) {
    const int row = blockIdx.x;
    const int t = threadIdx.x;
    const float4 v = ((const float4*)(in + (size_t)row * D_DIM))[t];
    float ss = v.x * v.x + v.y * v.y + v.z * v.z + v.w * v.w;
#pragma unroll
    for (int o = 1; o < 64; o <<= 1) ss += __shfl_xor(ss, o);
    __shared__ float red[4];
    if ((t & 63) == 0) red[t >> 6] = ss;
    __syncthreads();
    const float tot = red[0] + red[1] + red[2] + red[3];
    const float scale = 1.0f / fmaxf(sqrtf(tot), 1e-8f);
    ushort4 o;
    o.x = f2bf(v.x * scale);
    o.y = f2bf(v.y * scale);
    o.z = f2bf(v.z * scale);
    o.w = f2bf(v.w * scale);
    ((ushort4*)(out + (size_t)row * D_DIM))[t] = o;
}

__device__ __forceinline__ void gload_lds16(const void* g, void* l) {
    __builtin_amdgcn_global_load_lds(
        (const __attribute__((address_space(1))) void*)g,
        (__attribute__((address_space(3))) void*)l,
        16, 0, 0);
}

// Swizzled LDS fragment read: logical (row, kof elems) in a [256][32] bf16
// op-tile; stored byte = logical byte ^ ((row&3)<<4)  (involution, 16B-granular).
__device__ __forceinline__ bf16x8 lds_read_swz(const unsigned short* opbase, int row, int kof) {
    const int lin = row * 64 + kof * 2;
    const int byt = lin ^ ((row & 3) << 4);
    return *(const bf16x8*)((const char*)opbase + byt);
}

// One K-tile: 2 phases. Phase0: ds_read A(qr=0)x4 + Bx4, stage A of tile v+3.
// Phase1: ds_read A(qr=1)x4 (B frags reused), stage B of tile v+3.
// VM: vmcnt literal before end-of-tile barrier (-1 = none, last tile).
template<bool STAGE, int VM>
__device__ __forceinline__ void tile_body(
        int v,
        const unsigned short* __restrict__ A,
        const unsigned short* __restrict__ Bm,
        unsigned short* lds,
        int rowA0, int rowB0, int wid, int lane, int wr, int wc,
        int srow, int scol, f32x4 (&acc)[2][4][4])
{
    const unsigned short* bufA = lds + ((size_t)((v & 3) * 2 + 0)) * 8192;
    const unsigned short* bufB = lds + ((size_t)((v & 3) * 2 + 1)) * 8192;
    const int kof = (lane >> 4) * 8;   // 0,8,16,24 (K elems)
    const int rl  = lane & 15;

    bf16x8 af[4], bfr[4];

    // ---------- phase 0 ----------
#pragma unroll
    for (int m = 0; m < 4; ++m)
        af[m] = lds_read_swz(bufA, wr * 128 + m * 16 + rl, kof);
#pragma unroll
    for (int n = 0; n < 4; ++n)
        bfr[n] = lds_read_swz(bufB, wc * 64 + n * 16 + rl, kof);

    if constexpr (STAGE) {  // stage A of tile v+3
        const int u = v + 3, k0 = u * BKt;
        unsigned short* dst = lds + ((size_t)((u & 3) * 2 + 0)) * 8192;
#pragma unroll
        for (int j = 0; j < 2; ++j)
            gload_lds16(&A[(size_t)(rowA0 + srow + j * 128) * D_DIM + k0 + scol],
                        dst + ((size_t)(j * 512 + wid * 64)) * 8);
    }

    asm volatile("s_barrier" ::: "memory");
    asm volatile("s_waitcnt lgkmcnt(0)" ::: "memory");
    __builtin_amdgcn_s_setprio(1);
#pragma unroll
    for (int m = 0; m < 4; ++m)
#pragma unroll
        for (int n = 0; n < 4; ++n)
            acc[0][m][n] = __builtin_amdgcn_mfma_f32_16x16x32_bf16(
                af[m], bfr[n], acc[0][m][n], 0, 0, 0);
    __builtin_amdgcn_s_setprio(0);
    asm volatile("s_barrier" ::: "memory");

    // ---------- phase 1 ----------
#pragma unroll
    for (int m = 0; m < 4; ++m)
        af[m] = lds_read_swz(bufA, wr * 128 + 64 + m * 16 + rl, kof);

    if constexpr (STAGE) {  // stage B of tile v+3
        const int u = v + 3, k0 = u * BKt;
        unsigned short* dst = lds + ((size_t)((u & 3) * 2 + 1)) * 8192;
#pragma unroll
        for (int j = 0; j < 2; ++j)
            gload_lds16(&Bm[(size_t)(rowB0 + srow + j * 128) * D_DIM + k0 + scol],
                        dst + ((size_t)(j * 512 + wid * 64)) * 8);
    }

    asm volatile("s_barrier" ::: "memory");
    asm volatile("s_waitcnt lgkmcnt(0)" ::: "memory");
    __builtin_amdgcn_s_setprio(1);
#pragma unroll
    for (int m = 0; m < 4; ++m)
#pragma unroll
        for (int n = 0; n < 4; ++n)
            acc[1][m][n] = __builtin_amdgcn_mfma_f32_16x16x32_bf16(
                af[m], bfr[n], acc[1][m][n], 0, 0, 0);
    __builtin_amdgcn_s_setprio(0);

    if constexpr (VM == 8) asm volatile("s_waitcnt vmcnt(8)" ::: "memory");
    if constexpr (VM == 4) asm volatile("s_waitcnt vmcnt(4)" ::: "memory");
    if constexpr (VM == 0) asm volatile("s_waitcnt vmcnt(0)" ::: "memory");
    if constexpr (VM >= 0) asm volatile("s_barrier" ::: "memory");
}

__global__ __launch_bounds__(512, 2) void gemm256(
        const unsigned short* __restrict__ A,
        const unsigned short* __restrict__ Bm,
        float* __restrict__ Cg)
{
    __shared__ unsigned short lds[65536];  // 128 KiB: [buf 0..3][A,B][8192 ushorts]

    // chunked XCD swizzle: XCD x gets bm in [8x, 8x+8), all bn (8 A-panels + B in L2)
    const int nwg = gridDim.x;          // 512
    const int cpx = nwg >> 3;           // 64
    const int wg  = ((int)blockIdx.x & 7) * cpx + ((int)blockIdx.x >> 3);
    const int bm  = wg >> 3;            // 0..63
    const int bn  = wg & 7;             // 0..7
    const int rowA0 = bm * BMt;
    const int rowB0 = bn * BNt;

    const int tid  = threadIdx.x;
    const int lane = tid & 63;
    const int wid  = tid >> 6;          // 0..7
    const int wr   = wid >> 2;          // 0..1 -> 128-row half
    const int wc   = wid & 3;           // 0..3 -> 64-col slice

    // staging geometry: slot = j*512+tid covers a [256][32] bf16 op-tile, 16B/lane.
    // source pre-swizzled so linear gload_lds dest + swizzled ds_read match (rule #21)
    const int srow = tid >> 2;                                   // 0..127 (+128 for j=1)
    const int scol = (((tid & 3) ^ ((tid >> 2) & 3)) << 3);      // pre-swizzled K col

    f32x4 acc[2][4][4] = {};

    // prologue: stage tiles 0,1,2 (12 loads/wave), wait tile0 (leave 8 in flight)
#pragma unroll
    for (int u = 0; u < 3; ++u) {
        const int k0 = u * BKt;
        unsigned short* dA = lds + ((size_t)((u & 3) * 2 + 0)) * 8192;
        unsigned short* dB = lds + ((size_t)((u & 3) * 2 + 1)) * 8192;
#pragma unroll
        for (int j = 0; j < 2; ++j) {
            gload_lds16(&A [(size_t)(rowA0 + srow + j * 128) * D_DIM + k0 + scol],
                        dA + ((size_t)(j * 512 + wid * 64)) * 8);
            gload_lds16(&Bm[(size_t)(rowB0 + srow + j * 128) * D_DIM + k0 + scol],
                        dB + ((size_t)(j * 512 + wid * 64)) * 8);
        }
    }
    asm volatile("s_waitcnt vmcnt(8)" ::: "memory");
    asm volatile("s_barrier" ::: "memory");

    // main loop: tiles 0..28 stage tile v+3, vmcnt(8) per tile boundary
    for (int v = 0; v < NTILES - 3; ++v)
        tile_body<true, 8>(v, A, Bm, lds, rowA0, rowB0, wid, lane, wr, wc, srow, scol, acc);
    // epilogue tiles: drain 8 -> 4 -> 0
    tile_body<false, 4>(NTILES - 3, A, Bm, lds, rowA0, rowB0, wid, lane, wr, wc, srow, scol, acc);
    tile_body<false, 0>(NTILES - 2, A, Bm, lds, rowA0, rowB0, wid, lane, wr, wc, srow, scol, acc);
    tile_body<false, -1>(NTILES - 1, A, Bm, lds, rowA0, rowB0, wid, lane, wr, wc, srow, scol, acc);

    // epilogue: C/D layout col=lane&15, row=(lane>>4)*4+j (m89-verified)
    const int crow0 = rowA0 + wr * 128 + (lane >> 4) * 4;
    const int ccol0 = rowB0 + wc * 64 + (lane & 15);
#pragma unroll
    for (int qr = 0; qr < 2; ++qr)
#pragma unroll
        for (int m = 0; m < 4; ++m)
#pragma unroll
            for (int n = 0; n < 4; ++n)
#pragma unroll
                for (int j = 0; j < 4; ++j)
                    Cg[(size_t)(crow0 + qr * 64 + m * 16 + j) * N_DIM + ccol0 + n * 16]
                        = acc[qr][m][n][j];
}

extern "C" void kernel_launch(void* const* d_in, const int* in_sizes, int n_in,
                              void* d_out, int out_size, void* d_ws, size_t ws_size,
                              hipStream_t stream) {
    const float* x = (const float*)d_in[0];   // [B, D]
    const float* a = (const float*)d_in[1];   // [C, D]
    float* out = (float*)d_out;               // [B, C]

    const int Bn = in_sizes[0] / D_DIM;  // 16384
    const int Cn = in_sizes[1] / D_DIM;  // 2048

    unsigned short* xn = (unsigned short*)d_ws;            // [B][D] bf16
    unsigned short* an = xn + (size_t)Bn * D_DIM;          // [C][D] bf16

    normalize_rows<<<Bn, 256, 0, stream>>>(x, xn);
    normalize_rows<<<Cn, 256, 0, stream>>>(a, an);

    const int grid = (Bn / BMt) * (Cn / BNt);  // 64 * 8 = 512
    gemm256<<<grid, 512, 0, stream>>>(xn, an, out);
}

// Round 3
// 96.735 us; speedup vs baseline: 1.3310x; 1.0684x over previous
//
#include <hip/hip_runtime.h>
#include <stdint.h>

// out[b,c] = <x_b/||x_b||, a_c/||a_c||>, B=16384, C=2048, D=1024, fp32 in/out.
// Pass 1: fp32 row-normalize -> bf16 into d_ws (HBM-BW-floor already).
// Pass 2: bf16 MFMA GEMM, m201 8-phase template: 256x256 tile, BK=64, 8 waves
//         (2Mx4N), 2 double-buffers (128 KiB), 4 phases/K-tile, counted
//         vmcnt(4) once per K-tile (T3+T4), (row&7)<<4 XOR swizzle (T2),
//         setprio around MFMA (T5), chunked XCD swizzle (T1).

#define D_DIM 1024
#define N_DIM 2048
#define BMt 256
#define BNt 256
#define BKt 64
#define NKT 16      // D_DIM / BKt

typedef __bf16 bf16x8 __attribute__((ext_vector_type(8)));
typedef float  f32x4  __attribute__((ext_vector_type(4)));

__device__ __forceinline__ unsigned short f2bf(float f) {
    union { float f; uint32_t u; } v; v.f = f;
    uint32_t r = v.u + 0x7fffu + ((v.u >> 16) & 1u);  // RNE
    return (unsigned short)(r >> 16);
}

__global__ __launch_bounds__(256) void normalize_rows(
        const float* __restrict__ in, unsigned short* __restrict__ out) {
    const int row = blockIdx.x;
    const int t = threadIdx.x;
    const float4 v = ((const float4*)(in + (size_t)row * D_DIM))[t];
    float ss = v.x * v.x + v.y * v.y + v.z * v.z + v.w * v.w;
#pragma unroll
    for (int o = 1; o < 64; o <<= 1) ss += __shfl_xor(ss, o);
    __shared__ float red[4];
    if ((t & 63) == 0) red[t >> 6] = ss;
    __syncthreads();
    const float tot = red[0] + red[1] + red[2] + red[3];
    const float scale = 1.0f / fmaxf(sqrtf(tot), 1e-8f);
    ushort4 o;
    o.x = f2bf(v.x * scale);
    o.y = f2bf(v.y * scale);
    o.z = f2bf(v.z * scale);
    o.w = f2bf(v.w * scale);
    ((ushort4*)(out + (size_t)row * D_DIM))[t] = o;
}

__device__ __forceinline__ void gload_lds16(const void* g, void* l) {
    __builtin_amdgcn_global_load_lds(
        (const __attribute__((address_space(1))) void*)g,
        (__attribute__((address_space(3))) void*)l,
        16, 0, 0);
}

// LDS op-tile: [256 rows][64 K] bf16, 128 B/row, 8 x 16B slots/row.
// Stored slot = logical slot ^ (row & 7)  -> ds_read_b128 conflict-free.
__device__ __forceinline__ bf16x8 lds_frag(const unsigned short* opb, int R, int t) {
    const int byt = R * 128 + ((t ^ (R & 7)) << 4);
    return *(const bf16x8*)((const char*)opb + byt);
}

// Stage one half-tile (128 rows x 64 K = 16 KB) with 2 gload_lds per thread.
// Linear LDS dest; global col pre-swizzled to invert the read swizzle (rule #21).
__device__ __forceinline__ void stage_half(
        const unsigned short* __restrict__ src, int grow0, int k0,
        unsigned short* dst_region, int tid, int wid) {
    const int gcol = (((tid & 7) ^ ((tid >> 3) & 7)) << 3);
    const int grow = (tid >> 3);
#pragma unroll
    for (int j = 0; j < 2; ++j)
        gload_lds16(&src[(size_t)(grow0 + j * 64 + grow) * D_DIM + k0 + gcol],
                    dst_region + ((size_t)(j * 512 + wid * 64)) * 8);
}

#define PH_BAR()  asm volatile("s_barrier" ::: "memory")
#define PH_LGKM() asm volatile("s_waitcnt lgkmcnt(0)" ::: "memory")

#define MFMA_QUAD(M0, N0)                                                     \
    __builtin_amdgcn_s_setprio(1);                                            \
    _Pragma("unroll") for (int m = 0; m < 4; ++m)                             \
    _Pragma("unroll") for (int n = 0; n < 2; ++n)                             \
    _Pragma("unroll") for (int kk = 0; kk < 2; ++kk)                          \
        acc[M0 + m][N0 + n] = __builtin_amdgcn_mfma_f32_16x16x32_bf16(        \
            af[M0 + m][kk], bf[N0 + n][kk], acc[M0 + m][N0 + n], 0, 0, 0);    \
    __builtin_amdgcn_s_setprio(0);

// MODE 0: steady (stage B(t+1) at ph0/ph1, A(t+2) at ph2/ph3, vmcnt(4))
// MODE 1: t=14 (stage B(15) only, vmcnt(0))
// MODE 2: t=15 (no stages, no boundary)
template<int MODE>
__device__ __forceinline__ void ktile(
        int t, const unsigned short* __restrict__ A,
        const unsigned short* __restrict__ Bm, unsigned short* lds,
        int rowA0, int rowB0, int tid, int wid, int wr, int wc,
        f32x4 (&acc)[8][4])
{
    const int lane = tid & 63;
    const int rl = lane & 15, ts = lane >> 4;
    unsigned short* bufA = lds + ((size_t)((t & 1) * 2 + 0)) * 16384;
    unsigned short* bufB = lds + ((size_t)((t & 1) * 2 + 1)) * 16384;
    unsigned short* nB   = lds + ((size_t)(((t + 1) & 1) * 2 + 1)) * 16384;  // B of t+1
    unsigned short* nA   = bufA;                                             // A of t+2 (same parity)

    bf16x8 af[8][2], bf[4][2];

    // ---- phase 0: read af[0-3], bf[0-1]; stage B0(t+1) ----
#pragma unroll
    for (int m = 0; m < 4; ++m)
#pragma unroll
        for (int kk = 0; kk < 2; ++kk)
            af[m][kk] = lds_frag(bufA, wr * 128 + m * 16 + rl, kk * 4 + ts);
#pragma unroll
    for (int n = 0; n < 2; ++n)
#pragma unroll
        for (int kk = 0; kk < 2; ++kk)
            bf[n][kk] = lds_frag(bufB, wc * 64 + n * 16 + rl, kk * 4 + ts);
    if constexpr (MODE <= 1)
        stage_half(Bm, rowB0 + 0, (t + 1) * BKt, nB + 0, tid, wid);
    PH_BAR(); PH_LGKM();
    MFMA_QUAD(0, 0)
    PH_BAR();

    // ---- phase 1: read af[4-7]; stage B1(t+1) ----
#pragma unroll
    for (int m = 4; m < 8; ++m)
#pragma unroll
        for (int kk = 0; kk < 2; ++kk)
            af[m][kk] = lds_frag(bufA, wr * 128 + m * 16 + rl, kk * 4 + ts);
    if constexpr (MODE <= 1)
        stage_half(Bm, rowB0 + 128, (t + 1) * BKt, nB + 8192, tid, wid);
    PH_BAR(); PH_LGKM();
    MFMA_QUAD(4, 0)
    PH_BAR();

    // ---- phase 2: read bf[2-3]; stage A0(t+2) ----
#pragma unroll
    for (int n = 2; n < 4; ++n)
#pragma unroll
        for (int kk = 0; kk < 2; ++kk)
            bf[n][kk] = lds_frag(bufB, wc * 64 + n * 16 + rl, kk * 4 + ts);
    if constexpr (MODE == 0)
        stage_half(A, rowA0 + 0, (t + 2) * BKt, nA + 0, tid, wid);
    PH_BAR(); PH_LGKM();
    MFMA_QUAD(0, 2)
    PH_BAR();

    // ---- phase 3: no reads; stage A1(t+2); boundary vmcnt ----
    if constexpr (MODE == 0)
        stage_half(A, rowA0 + 128, (t + 2) * BKt, nA + 8192, tid, wid);
    PH_BAR();
    MFMA_QUAD(4, 2)
    if constexpr (MODE == 0) asm volatile("s_waitcnt vmcnt(4)" ::: "memory");
    if constexpr (MODE == 1) asm volatile("s_waitcnt vmcnt(0)" ::: "memory");
    if constexpr (MODE <= 1) PH_BAR();
}

__global__ __launch_bounds__(512, 2) void gemm256(
        const unsigned short* __restrict__ A,
        const unsigned short* __restrict__ Bm,
        float* __restrict__ Cg)
{
    __shared__ unsigned short lds[65536];  // 128 KiB: [buf0/1][A,B][16384]

    const int nwg = gridDim.x;          // 512
    const int cpx = nwg >> 3;           // 64
    const int wg  = ((int)blockIdx.x & 7) * cpx + ((int)blockIdx.x >> 3);
    const int bm  = wg >> 3;            // 0..63  (8 consecutive wg share bm -> same XCD)
    const int bn  = wg & 7;             // 0..7
    const int rowA0 = bm * BMt;
    const int rowB0 = bn * BNt;

    const int tid  = threadIdx.x;
    const int lane = tid & 63;
    const int wid  = tid >> 6;          // 0..7
    const int wr   = wid >> 2;          // 0..1 -> 128-row half
    const int wc   = wid & 3;           // 0..3 -> 64-col slice

    f32x4 acc[8][4] = {};

    // prologue: stage T0.{A0,A1,B0,B1}, T1.{A0,A1} (12 loads); leave T1.A* in flight
    {
        unsigned short* b0A = lds + 0;
        unsigned short* b0B = lds + 16384;
        unsigned short* b1A = lds + 32768;
        stage_half(A,  rowA0 + 0,   0,   b0A + 0,    tid, wid);
        stage_half(A,  rowA0 + 128, 0,   b0A + 8192, tid, wid);
        stage_half(Bm, rowB0 + 0,   0,   b0B + 0,    tid, wid);
        stage_half(Bm, rowB0 + 128, 0,   b0B + 8192, tid, wid);
        stage_half(A,  rowA0 + 0,   BKt, b1A + 0,    tid, wid);
        stage_half(A,  rowA0 + 128, BKt, b1A + 8192, tid, wid);
    }
    asm volatile("s_waitcnt vmcnt(4)" ::: "memory");
    PH_BAR();

    for (int t = 0; t < NKT - 2; ++t)
        ktile<0>(t, A, Bm, lds, rowA0, rowB0, tid, wid, wr, wc, acc);
    ktile<1>(NKT - 2, A, Bm, lds, rowA0, rowB0, tid, wid, wr, wc, acc);
    ktile<2>(NKT - 1, A, Bm, lds, rowA0, rowB0, tid, wid, wr, wc, acc);

    // epilogue: C/D layout col=lane&15, row=(lane>>4)*4+j (m89-verified)
    const int crow0 = rowA0 + wr * 128 + (lane >> 4) * 4;
    const int ccol0 = rowB0 + wc * 64 + (lane & 15);
#pragma unroll
    for (int m = 0; m < 8; ++m)
#pragma unroll
        for (int n = 0; n < 4; ++n)
#pragma unroll
            for (int j = 0; j < 4; ++j)
                Cg[(size_t)(crow0 + m * 16 + j) * N_DIM + ccol0 + n * 16] = acc[m][n][j];
}

extern "C" void kernel_launch(void* const* d_in, const int* in_sizes, int n_in,
                              void* d_out, int out_size, void* d_ws, size_t ws_size,
                              hipStream_t stream) {
    const float* x = (const float*)d_in[0];   // [B, D]
    const float* a = (const float*)d_in[1];   // [C, D]
    float* out = (float*)d_out;               // [B, C]

    const int Bn = in_sizes[0] / D_DIM;  // 16384
    const int Cn = in_sizes[1] / D_DIM;  // 2048

    unsigned short* xn = (unsigned short*)d_ws;            // [B][D] bf16
    unsigned short* an = xn + (size_t)Bn * D_DIM;          // [C][D] bf16

    normalize_rows<<<Bn, 256, 0, stream>>>(x, xn);
    normalize_rows<<<Cn, 256, 0, stream>>>(a, an);

    const int grid = (Bn / BMt) * (Cn / BNt);  // 64 * 8 = 512
    gemm256<<<grid, 512, 0, stream>>>(xn, an, out);
}

// Round 5
// 94.425 us; speedup vs baseline: 1.3635x; 1.0245x over previous
//
#include <hip/hip_runtime.h>
#include <stdint.h>

// out[b,c] = <x_b/||x_b||, a_c/||a_c||>, B=16384, C=2048, D=1024, fp32 in/out.
// Pass 1: fp32 row-normalize -> bf16 into d_ws.
// Pass 2: bf16 MFMA GEMM, 256x256 tile, BK=64, 8 waves (2Mx4N), double-buffered
//   LDS (128 KiB), 4 phases/K-tile with READ-AHEAD pipelining: each phase's
//   MFMA consumes fragments ds_read one phase earlier (LDS || MFMA overlap).
//   RACE RULE (R4 fix): any read of LDS staged by OTHER waves must sit behind
//   a barrier that all waves reach AFTER their own counted vmcnt guard
//   ("vmcnt -> barrier -> read"). R4's ph3 bfN0' read violated this; ph3 now
//   has an extra s_barrier between the boundary vmcnt and the read-ahead.

#define D_DIM 1024
#define N_DIM 2048
#define BMt 256
#define BNt 256
#define BKt 64
#define NKT 16      // D_DIM / BKt

typedef __bf16 bf16x8 __attribute__((ext_vector_type(8)));
typedef float  f32x4  __attribute__((ext_vector_type(4)));

__device__ __forceinline__ unsigned short f2bf(float f) {
    union { float f; uint32_t u; } v; v.f = f;
    uint32_t r = v.u + 0x7fffu + ((v.u >> 16) & 1u);  // RNE
    return (unsigned short)(r >> 16);
}

__global__ __launch_bounds__(256) void normalize_rows(
        const float* __restrict__ in, unsigned short* __restrict__ out) {
    const int row = blockIdx.x;
    const int t = threadIdx.x;
    const float4 v = ((const float4*)(in + (size_t)row * D_DIM))[t];
    float ss = v.x * v.x + v.y * v.y + v.z * v.z + v.w * v.w;
#pragma unroll
    for (int o = 1; o < 64; o <<= 1) ss += __shfl_xor(ss, o);
    __shared__ float red[4];
    if ((t & 63) == 0) red[t >> 6] = ss;
    __syncthreads();
    const float tot = red[0] + red[1] + red[2] + red[3];
    const float scale = 1.0f / fmaxf(sqrtf(tot), 1e-8f);
    ushort4 o;
    o.x = f2bf(v.x * scale);
    o.y = f2bf(v.y * scale);
    o.z = f2bf(v.z * scale);
    o.w = f2bf(v.w * scale);
    ((ushort4*)(out + (size_t)row * D_DIM))[t] = o;
}

__device__ __forceinline__ void gload_lds16(const void* g, void* l) {
    __builtin_amdgcn_global_load_lds(
        (const __attribute__((address_space(1))) void*)g,
        (__attribute__((address_space(3))) void*)l,
        16, 0, 0);
}

// LDS op-tile: [256 rows][64 K] bf16, 128 B/row, 8 x 16B slots/row.
// Stored slot = logical slot ^ (row & 7)  -> ds_read_b128 conflict-free.
__device__ __forceinline__ bf16x8 lds_frag(const unsigned short* opb, int R, int t) {
    const int byt = R * 128 + ((t ^ (R & 7)) << 4);
    return *(const bf16x8*)((const char*)opb + byt);
}

// Stage one half-tile (128 rows x 64 K = 16 KB): 2 gload_lds per thread.
// Linear LDS dest; global col pre-swizzled to invert the read swizzle.
__device__ __forceinline__ void stage_half(
        const unsigned short* __restrict__ src, int grow0, int k0,
        unsigned short* dst_region, int tid, int wid) {
    const int gcol = (((tid & 7) ^ ((tid >> 3) & 7)) << 3);
    const int grow = (tid >> 3);
#pragma unroll
    for (int j = 0; j < 2; ++j)
        gload_lds16(&src[(size_t)(grow0 + j * 64 + grow) * D_DIM + k0 + gcol],
                    dst_region + ((size_t)(j * 512 + wid * 64)) * 8);
}

#define PH_BAR()   asm volatile("s_barrier" ::: "memory")
#define PH_LGKM0() asm volatile("s_waitcnt lgkmcnt(0)" ::: "memory")
#define VMCNT4()   asm volatile("s_waitcnt vmcnt(4)" ::: "memory")
#define VMCNT0()   asm volatile("s_waitcnt vmcnt(0)" ::: "memory")

// 16-MFMA quadrant: acc[MOFF..MOFF+3][NOFF..NOFF+1] += AF x BF
#define MFMA_Q(AF, BF, MOFF, NOFF)                                            \
    __builtin_amdgcn_s_setprio(1);                                            \
    _Pragma("unroll") for (int m = 0; m < 4; ++m)                             \
    _Pragma("unroll") for (int n = 0; n < 2; ++n)                             \
    _Pragma("unroll") for (int kk = 0; kk < 2; ++kk)                          \
        acc[(MOFF) + m][(NOFF) + n] = __builtin_amdgcn_mfma_f32_16x16x32_bf16(\
            AF[m][kk], BF[n][kk], acc[(MOFF) + m][(NOFF) + n], 0, 0, 0);      \
    __builtin_amdgcn_s_setprio(0);

// Quadrant order: Q0(M0,N0) Q1(M0,N1) Q2(M1,N1) Q3(M1,N0).
// All MFMA inputs were ds_read >=1 phase earlier. Per-phase reads: 4/8/8/4.
// Cross-wave read-ahead guards:
//   afA'(t+1) @ph2 : every wave's VMCNT4 at end-ph1 precedes the ph2 barrier.
//   bfN0'(t+1)@ph3 : every wave's boundary vmcnt precedes the EXTRA barrier,
//                    read sits after it (R4 race fix).
// MODE 0: t=0..13 (stage B(t+1) ph0/ph1, A(t+2) ph2/ph3, vmcnt(4) x2)
// MODE 1: t=14 (stage B(15) only; vmcnt(4) end-ph1, vmcnt(0) end-ph3)
// MODE 2: t=15 (no stages, no read-ahead into next tile)
template<int MODE>
__device__ __forceinline__ void ktile(
        int t, const unsigned short* __restrict__ A,
        const unsigned short* __restrict__ Bm, unsigned short* lds,
        int rowA0, int rowB0, int tid, int wid, int wr, int wc,
        bf16x8 (&afA)[4][2], bf16x8 (&afB)[4][2],
        bf16x8 (&bfN0)[2][2], bf16x8 (&bfN1)[2][2],
        f32x4 (&acc)[8][4])
{
    const int lane = tid & 63;
    const int rl = lane & 15, ts = lane >> 4;
    unsigned short* bufA = lds + ((size_t)((t & 1) * 2 + 0)) * 16384;       // A(t)
    unsigned short* bufB = lds + ((size_t)((t & 1) * 2 + 1)) * 16384;       // B(t)
    unsigned short* nxA  = lds + ((size_t)(((t + 1) & 1) * 2 + 0)) * 16384; // A(t+1)
    unsigned short* stB  = lds + ((size_t)(((t + 1) & 1) * 2 + 1)) * 16384; // B(t+1) dst
    unsigned short* stA  = bufA;                                            // A(t+2) dst

    // ---- ph0: MFMA Q0 (afA,bfN0 from prev phases); read bfN1; stage B0(t+1)
    PH_BAR();
    MFMA_Q(afA, bfN0, 0, 0)
#pragma unroll
    for (int n = 0; n < 2; ++n)
#pragma unroll
        for (int kk = 0; kk < 2; ++kk)
            bfN1[n][kk] = lds_frag(bufB, wc * 64 + 32 + n * 16 + rl, kk * 4 + ts);
    if constexpr (MODE <= 1)
        stage_half(Bm, rowB0 + 0, (t + 1) * BKt, stB + 0, tid, wid);

    // ---- ph1: MFMA Q1; read afB (A(t) M1); stage B1(t+1); guards
    PH_BAR();
    MFMA_Q(afA, bfN1, 0, 2)
#pragma unroll
    for (int m = 0; m < 4; ++m)
#pragma unroll
        for (int kk = 0; kk < 2; ++kk)
            afB[m][kk] = lds_frag(bufA, wr * 128 + 64 + m * 16 + rl, kk * 4 + ts);
    if constexpr (MODE <= 1)
        stage_half(Bm, rowB0 + 128, (t + 1) * BKt, stB + 8192, tid, wid);
    if constexpr (MODE == 0) PH_LGKM0();     // A(t)-region reads complete before restage
    if constexpr (MODE <= 1) VMCNT4();       // my A(t+1) loads landed (before ph2 barrier)

    // ---- ph2: MFMA Q2; read afA' (A(t+1) M0, all waves vmcnt'd); stage A0(t+2)
    PH_BAR();
    MFMA_Q(afB, bfN1, 4, 2)
    if constexpr (MODE <= 1) {
#pragma unroll
        for (int m = 0; m < 4; ++m)
#pragma unroll
            for (int kk = 0; kk < 2; ++kk)
                afA[m][kk] = lds_frag(nxA, wr * 128 + m * 16 + rl, kk * 4 + ts);
    }
    if constexpr (MODE == 0)
        stage_half(A, rowA0 + 0, (t + 2) * BKt, stA + 0, tid, wid);

    // ---- ph3: MFMA Q3; stage A1(t+2); boundary vmcnt; BARRIER; read bfN0'(t+1)
    PH_BAR();
    MFMA_Q(afB, bfN0, 4, 0)
    if constexpr (MODE == 0) {
        stage_half(A, rowA0 + 128, (t + 2) * BKt, stA + 8192, tid, wid);
        VMCNT4();                            // my B(t+1) loads landed
    }
    if constexpr (MODE == 1) VMCNT0();       // drain B(15)
    if constexpr (MODE <= 1) {
        PH_BAR();                            // ALL waves' B(t+1) landed (race fix)
#pragma unroll
        for (int n = 0; n < 2; ++n)
#pragma unroll
            for (int kk = 0; kk < 2; ++kk)
                bfN0[n][kk] = lds_frag(stB, wc * 64 + n * 16 + rl, kk * 4 + ts);
    }
}

__global__ __launch_bounds__(512, 2) void gemm256(
        const unsigned short* __restrict__ A,
        const unsigned short* __restrict__ Bm,
        float* __restrict__ Cg)
{
    __shared__ unsigned short lds[65536];  // 128 KiB: 4 regions x 32 KB

    const int nwg = gridDim.x;          // 512
    const int cpx = nwg >> 3;           // 64
    const int wg  = ((int)blockIdx.x & 7) * cpx + ((int)blockIdx.x >> 3);
    const int bm  = wg >> 3;            // 0..63
    const int bn  = wg & 7;             // 0..7
    const int rowA0 = bm * BMt;
    const int rowB0 = bn * BNt;

    const int tid  = threadIdx.x;
    const int lane = tid & 63;
    const int wid  = tid >> 6;          // 0..7
    const int wr   = wid >> 2;          // 0..1 -> 128-row half
    const int wc   = wid & 3;           // 0..3 -> 64-col slice
    const int rl = lane & 15, ts = lane >> 4;

    bf16x8 afA[4][2], afB[4][2], bfN0[2][2], bfN1[2][2];
    f32x4 acc[8][4] = {};

    // prologue: stage A(0), B(0), A(1); vmcnt(4) -> barrier -> preload afA, bfN0
    {
        unsigned short* r00 = lds + 0;          // A(0)
        unsigned short* r01 = lds + 16384;      // B(0)
        unsigned short* r10 = lds + 32768;      // A(1)
        stage_half(A,  rowA0 + 0,   0,   r00 + 0,    tid, wid);
        stage_half(A,  rowA0 + 128, 0,   r00 + 8192, tid, wid);
        stage_half(Bm, rowB0 + 0,   0,   r01 + 0,    tid, wid);
        stage_half(Bm, rowB0 + 128, 0,   r01 + 8192, tid, wid);
        stage_half(A,  rowA0 + 0,   BKt, r10 + 0,    tid, wid);
        stage_half(A,  rowA0 + 128, BKt, r10 + 8192, tid, wid);
        VMCNT4();
        PH_BAR();
#pragma unroll
        for (int m = 0; m < 4; ++m)
#pragma unroll
            for (int kk = 0; kk < 2; ++kk)
                afA[m][kk] = lds_frag(r00, wr * 128 + m * 16 + rl, kk * 4 + ts);
#pragma unroll
        for (int n = 0; n < 2; ++n)
#pragma unroll
            for (int kk = 0; kk < 2; ++kk)
                bfN0[n][kk] = lds_frag(r01, wc * 64 + n * 16 + rl, kk * 4 + ts);
    }

    for (int t = 0; t < NKT - 2; ++t)
        ktile<0>(t, A, Bm, lds, rowA0, rowB0, tid, wid, wr, wc, afA, afB, bfN0, bfN1, acc);
    ktile<1>(NKT - 2, A, Bm, lds, rowA0, rowB0, tid, wid, wr, wc, afA, afB, bfN0, bfN1, acc);
    ktile<2>(NKT - 1, A, Bm, lds, rowA0, rowB0, tid, wid, wr, wc, afA, afB, bfN0, bfN1, acc);

    // epilogue: C/D layout col=lane&15, row=(lane>>4)*4+j (m89-verified)
    const int crow0 = rowA0 + wr * 128 + (lane >> 4) * 4;
    const int ccol0 = rowB0 + wc * 64 + (lane & 15);
#pragma unroll
    for (int m = 0; m < 8; ++m)
#pragma unroll
        for (int n = 0; n < 4; ++n)
#pragma unroll
            for (int j = 0; j < 4; ++j)
                Cg[(size_t)(crow0 + m * 16 + j) * N_DIM + ccol0 + n * 16] = acc[m][n][j];
}

extern "C" void kernel_launch(void* const* d_in, const int* in_sizes, int n_in,
                              void* d_out, int out_size, void* d_ws, size_t ws_size,
                              hipStream_t stream) {
    const float* x = (const float*)d_in[0];   // [B, D]
    const float* a = (const float*)d_in[1];   // [C, D]
    float* out = (float*)d_out;               // [B, C]

    const int Bn = in_sizes[0] / D_DIM;  // 16384
    const int Cn = in_sizes[1] / D_DIM;  // 2048

    unsigned short* xn = (unsigned short*)d_ws;            // [B][D] bf16
    unsigned short* an = xn + (size_t)Bn * D_DIM;          // [C][D] bf16

    normalize_rows<<<Bn, 256, 0, stream>>>(x, xn);
    normalize_rows<<<Cn, 256, 0, stream>>>(a, an);

    const int grid = (Bn / BMt) * (Cn / BNt);  // 64 * 8 = 512
    gemm256<<<grid, 512, 0, stream>>>(xn, an, out);
}

// Round 6
// 93.360 us; speedup vs baseline: 1.3791x; 1.0114x over previous
//
#include <hip/hip_runtime.h>
#include <stdint.h>

// out[b,c] = <x_b/||x_b||, a_c/||a_c||>, B=16384, C=2048, D=1024, fp32 in/out.
// Pass 1: fp32 row-normalize -> bf16 into d_ws (single merged launch).
// Pass 2: bf16 MFMA GEMM, 256x256 tile, BK=64, 8 waves (2Mx4N), double-buffered
//   LDS (128 KiB), 4 phases/K-tile. R6 change vs R5: within each phase, LDS
//   reads are issued BEFORE the setprio'd MFMA cluster (in-order wave issue ->
//   ds_reads drain UNDER the MFMA burst instead of after it). Cross-tile
//   read-aheads (afA' ph2, bfN0' ph3) stay after the MFMA (register WAR: their
//   destination regs are consumed by that phase's MFMA; duplicating them would
//   blow the 256-unified-reg/wave budget at 2 waves/SIMD).
//   Race rule (from R4): cross-wave LDS read-ahead sits behind a barrier that
//   every wave reaches AFTER its own counted-vmcnt guard.
//     afA'(t+1) @ph2 : vmcnt(4) end-ph1 -> ph2 barrier -> read.
//     bfN0'(t+1)@ph3 : vmcnt(2) end-ph2 -> ph3 barrier -> read.
//   A-restage guard: lgkmcnt(0) end-ph1 (all my ds_reads of A(t)/B(t) drained
//   before A(t+2) DMA lands in A(t)'s region; >=1 barrier separates).

#define D_DIM 1024
#define N_DIM 2048
#define BMt 256
#define BNt 256
#define BKt 64
#define NKT 16      // D_DIM / BKt

typedef __bf16 bf16x8 __attribute__((ext_vector_type(8)));
typedef float  f32x4  __attribute__((ext_vector_type(4)));

__device__ __forceinline__ unsigned short f2bf(float f) {
    union { float f; uint32_t u; } v; v.f = f;
    uint32_t r = v.u + 0x7fffu + ((v.u >> 16) & 1u);  // RNE
    return (unsigned short)(r >> 16);
}

// One block per row (X rows then A rows): 256 threads x float4 = 1024 floats.
__global__ __launch_bounds__(256) void normalize_rows(
        const float* __restrict__ x, const float* __restrict__ a,
        unsigned short* __restrict__ xn, unsigned short* __restrict__ an,
        int Bn) {
    const int blk = blockIdx.x;
    const float* in = (blk < Bn) ? x : a;
    unsigned short* out = (blk < Bn) ? xn : an;
    const int row = (blk < Bn) ? blk : blk - Bn;
    const int t = threadIdx.x;
    const float4 v = ((const float4*)(in + (size_t)row * D_DIM))[t];
    float ss = v.x * v.x + v.y * v.y + v.z * v.z + v.w * v.w;
#pragma unroll
    for (int o = 1; o < 64; o <<= 1) ss += __shfl_xor(ss, o);
    __shared__ float red[4];
    if ((t & 63) == 0) red[t >> 6] = ss;
    __syncthreads();
    const float tot = red[0] + red[1] + red[2] + red[3];
    const float scale = 1.0f / fmaxf(sqrtf(tot), 1e-8f);
    ushort4 o;
    o.x = f2bf(v.x * scale);
    o.y = f2bf(v.y * scale);
    o.z = f2bf(v.z * scale);
    o.w = f2bf(v.w * scale);
    ((ushort4*)(out + (size_t)row * D_DIM))[t] = o;
}

__device__ __forceinline__ void gload_lds16(const void* g, void* l) {
    __builtin_amdgcn_global_load_lds(
        (const __attribute__((address_space(1))) void*)g,
        (__attribute__((address_space(3))) void*)l,
        16, 0, 0);
}

// LDS op-tile: [256 rows][64 K] bf16, 128 B/row, 8 x 16B slots/row.
// Stored slot = logical slot ^ (row & 7)  -> ds_read_b128 conflict-free.
__device__ __forceinline__ bf16x8 lds_frag(const unsigned short* opb, int R, int t) {
    const int byt = R * 128 + ((t ^ (R & 7)) << 4);
    return *(const bf16x8*)((const char*)opb + byt);
}

// Stage one half-tile (128 rows x 64 K = 16 KB): 2 gload_lds per thread.
// Linear LDS dest; global col pre-swizzled to invert the read swizzle.
__device__ __forceinline__ void stage_half(
        const unsigned short* __restrict__ src, int grow0, int k0,
        unsigned short* dst_region, int tid, int wid) {
    const int gcol = (((tid & 7) ^ ((tid >> 3) & 7)) << 3);
    const int grow = (tid >> 3);
#pragma unroll
    for (int j = 0; j < 2; ++j)
        gload_lds16(&src[(size_t)(grow0 + j * 64 + grow) * D_DIM + k0 + gcol],
                    dst_region + ((size_t)(j * 512 + wid * 64)) * 8);
}

#define PH_BAR()   asm volatile("s_barrier" ::: "memory")
#define PH_LGKM0() asm volatile("s_waitcnt lgkmcnt(0)" ::: "memory")
#define VMCNT4()   asm volatile("s_waitcnt vmcnt(4)" ::: "memory")
#define VMCNT2()   asm volatile("s_waitcnt vmcnt(2)" ::: "memory")
#define VMCNT0()   asm volatile("s_waitcnt vmcnt(0)" ::: "memory")

// 16-MFMA quadrant: acc[MOFF..MOFF+3][NOFF..NOFF+1] += AF x BF
#define MFMA_Q(AF, BF, MOFF, NOFF)                                            \
    __builtin_amdgcn_s_setprio(1);                                            \
    _Pragma("unroll") for (int m = 0; m < 4; ++m)                             \
    _Pragma("unroll") for (int n = 0; n < 2; ++n)                             \
    _Pragma("unroll") for (int kk = 0; kk < 2; ++kk)                          \
        acc[(MOFF) + m][(NOFF) + n] = __builtin_amdgcn_mfma_f32_16x16x32_bf16(\
            AF[m][kk], BF[n][kk], acc[(MOFF) + m][(NOFF) + n], 0, 0, 0);      \
    __builtin_amdgcn_s_setprio(0);

// Quadrants: Q0(M0,N0)@ph0 Q1(M0,N1)@ph1 Q2(M1,N1)@ph2 Q3(M1,N0)@ph3.
// Per-phase: [bar] -> {intra-tile reads | stage} -> MFMA -> {cross-tile reads}
//            -> {guards}.
// MODE 0: t=0..13   MODE 1: t=14 (no A(16) stage)   MODE 2: t=15 (tail)
template<int MODE>
__device__ __forceinline__ void ktile(
        int t, const unsigned short* __restrict__ A,
        const unsigned short* __restrict__ Bm, unsigned short* lds,
        int rowA0, int rowB0, int tid, int wid, int wr, int wc,
        bf16x8 (&afA)[4][2], bf16x8 (&afB)[4][2],
        bf16x8 (&bfN0)[2][2], bf16x8 (&bfN1)[2][2],
        f32x4 (&acc)[8][4])
{
    const int lane = tid & 63;
    const int rl = lane & 15, ts = lane >> 4;
    unsigned short* bufA = lds + ((size_t)((t & 1) * 2 + 0)) * 16384;       // A(t)
    unsigned short* bufB = lds + ((size_t)((t & 1) * 2 + 1)) * 16384;       // B(t)
    unsigned short* nxA  = lds + ((size_t)(((t + 1) & 1) * 2 + 0)) * 16384; // A(t+1)
    unsigned short* nxB  = lds + ((size_t)(((t + 1) & 1) * 2 + 1)) * 16384; // B(t+1) dst
    unsigned short* stA  = bufA;                                            // A(t+2) dst

    // ---- ph0: reads bfN1 FIRST, stage B0(t+1); MFMA Q0 (afA x bfN0)
    PH_BAR();
#pragma unroll
    for (int n = 0; n < 2; ++n)
#pragma unroll
        for (int kk = 0; kk < 2; ++kk)
            bfN1[n][kk] = lds_frag(bufB, wc * 64 + 32 + n * 16 + rl, kk * 4 + ts);
    if constexpr (MODE <= 1)
        stage_half(Bm, rowB0 + 0, (t + 1) * BKt, nxB + 0, tid, wid);
    MFMA_Q(afA, bfN0, 0, 0)

    // ---- ph1: reads afB FIRST, stage B1(t+1); MFMA Q1 (afA x bfN1); guards
    PH_BAR();
#pragma unroll
    for (int m = 0; m < 4; ++m)
#pragma unroll
        for (int kk = 0; kk < 2; ++kk)
            afB[m][kk] = lds_frag(bufA, wr * 128 + 64 + m * 16 + rl, kk * 4 + ts);
    if constexpr (MODE <= 1)
        stage_half(Bm, rowB0 + 128, (t + 1) * BKt, nxB + 8192, tid, wid);
    MFMA_Q(afA, bfN1, 0, 2)
    if constexpr (MODE <= 1) {
        PH_LGKM0();   // my A(t)/B(t) ds_reads drained before A(t+2) DMA region reuse
        VMCNT4();     // A(t+1) landed (outstanding: A(t+1) 4 + B(t+1) 4)
    }

    // ---- ph2: stage A0(t+2); MFMA Q2 (afB x bfN1); read afA'(t+1) AFTER; guard
    PH_BAR();
    if constexpr (MODE == 0)
        stage_half(A, rowA0 + 0, (t + 2) * BKt, stA + 0, tid, wid);
    MFMA_Q(afB, bfN1, 4, 2)
    if constexpr (MODE <= 1) {
#pragma unroll
        for (int m = 0; m < 4; ++m)
#pragma unroll
            for (int kk = 0; kk < 2; ++kk)
                afA[m][kk] = lds_frag(nxA, wr * 128 + m * 16 + rl, kk * 4 + ts);
    }
    if constexpr (MODE == 0) VMCNT2();   // B(t+1) landed (leaves A0(t+2) in flight)
    if constexpr (MODE == 1) VMCNT0();   // drain B(15)

    // ---- ph3: stage A1(t+2); MFMA Q3 (afB x bfN0); read bfN0'(t+1) AFTER
    PH_BAR();
    if constexpr (MODE == 0)
        stage_half(A, rowA0 + 128, (t + 2) * BKt, stA + 8192, tid, wid);
    MFMA_Q(afB, bfN0, 4, 0)
    if constexpr (MODE <= 1) {
#pragma unroll
        for (int n = 0; n < 2; ++n)
#pragma unroll
            for (int kk = 0; kk < 2; ++kk)
                bfN0[n][kk] = lds_frag(nxB, wc * 64 + n * 16 + rl, kk * 4 + ts);
    }
}

__global__ __launch_bounds__(512, 2) void gemm256(
        const unsigned short* __restrict__ A,
        const unsigned short* __restrict__ Bm,
        float* __restrict__ Cg)
{
    __shared__ unsigned short lds[65536];  // 128 KiB: 4 regions x 32 KB

    const int nwg = gridDim.x;          // 512
    const int cpx = nwg >> 3;           // 64
    const int wg  = ((int)blockIdx.x & 7) * cpx + ((int)blockIdx.x >> 3);
    const int bm  = wg >> 3;            // 0..63
    const int bn  = wg & 7;             // 0..7
    const int rowA0 = bm * BMt;
    const int rowB0 = bn * BNt;

    const int tid  = threadIdx.x;
    const int lane = tid & 63;
    const int wid  = tid >> 6;          // 0..7
    const int wr   = wid >> 2;          // 0..1 -> 128-row half
    const int wc   = wid & 3;           // 0..3 -> 64-col slice
    const int rl = lane & 15, ts = lane >> 4;

    bf16x8 afA[4][2], afB[4][2], bfN0[2][2], bfN1[2][2];
    f32x4 acc[8][4] = {};

    // prologue: stage A(0), B(0), A(1); vmcnt(4) -> barrier -> preload afA, bfN0
    {
        unsigned short* r00 = lds + 0;          // A(0)
        unsigned short* r01 = lds + 16384;      // B(0)
        unsigned short* r10 = lds + 32768;      // A(1)
        stage_half(A,  rowA0 + 0,   0,   r00 + 0,    tid, wid);
        stage_half(A,  rowA0 + 128, 0,   r00 + 8192, tid, wid);
        stage_half(Bm, rowB0 + 0,   0,   r01 + 0,    tid, wid);
        stage_half(Bm, rowB0 + 128, 0,   r01 + 8192, tid, wid);
        stage_half(A,  rowA0 + 0,   BKt, r10 + 0,    tid, wid);
        stage_half(A,  rowA0 + 128, BKt, r10 + 8192, tid, wid);
        VMCNT4();
        PH_BAR();
#pragma unroll
        for (int m = 0; m < 4; ++m)
#pragma unroll
            for (int kk = 0; kk < 2; ++kk)
                afA[m][kk] = lds_frag(r00, wr * 128 + m * 16 + rl, kk * 4 + ts);
#pragma unroll
        for (int n = 0; n < 2; ++n)
#pragma unroll
            for (int kk = 0; kk < 2; ++kk)
                bfN0[n][kk] = lds_frag(r01, wc * 64 + n * 16 + rl, kk * 4 + ts);
    }

    for (int t = 0; t < NKT - 2; ++t)
        ktile<0>(t, A, Bm, lds, rowA0, rowB0, tid, wid, wr, wc, afA, afB, bfN0, bfN1, acc);
    ktile<1>(NKT - 2, A, Bm, lds, rowA0, rowB0, tid, wid, wr, wc, afA, afB, bfN0, bfN1, acc);
    ktile<2>(NKT - 1, A, Bm, lds, rowA0, rowB0, tid, wid, wr, wc, afA, afB, bfN0, bfN1, acc);

    // epilogue: C/D layout col=lane&15, row=(lane>>4)*4+j (m89-verified)
    const int crow0 = rowA0 + wr * 128 + (lane >> 4) * 4;
    const int ccol0 = rowB0 + wc * 64 + (lane & 15);
#pragma unroll
    for (int m = 0; m < 8; ++m)
#pragma unroll
        for (int n = 0; n < 4; ++n)
#pragma unroll
            for (int j = 0; j < 4; ++j)
                Cg[(size_t)(crow0 + m * 16 + j) * N_DIM + ccol0 + n * 16] = acc[m][n][j];
}

extern "C" void kernel_launch(void* const* d_in, const int* in_sizes, int n_in,
                              void* d_out, int out_size, void* d_ws, size_t ws_size,
                              hipStream_t stream) {
    const float* x = (const float*)d_in[0];   // [B, D]
    const float* a = (const float*)d_in[1];   // [C, D]
    float* out = (float*)d_out;               // [B, C]

    const int Bn = in_sizes[0] / D_DIM;  // 16384
    const int Cn = in_sizes[1] / D_DIM;  // 2048

    unsigned short* xn = (unsigned short*)d_ws;            // [B][D] bf16
    unsigned short* an = xn + (size_t)Bn * D_DIM;          // [C][D] bf16

    normalize_rows<<<Bn + Cn, 256, 0, stream>>>(x, a, xn, an, Bn);

    const int grid = (Bn / BMt) * (Cn / BNt);  // 64 * 8 = 512
    gemm256<<<grid, 512, 0, stream>>>(xn, an, out);
}